// Round 13
// baseline (255.538 us; speedup 1.0000x reference)
//
#include <hip/hip_runtime.h>
#include <hip/hip_bf16.h>
#include <math.h>

#define NN    20000
#define MP1   20224          // 79*256 padded rows for gemm1
#define NP    20096          // 157*128 padded rows for gemm2 A
#define E0    160000
#define EL    180000
#define NG    64
#define INDIM 1304
#define K1P   1344           // K padded to multiple of 64 (21 K-tiles)
#define GNT   21             // K1P/64
#define GNX   3              // 768/256
#define GMB   79             // M blocks
#define NWG1  (GMB * GNX)    // 237 gemm blocks
#define FB    19             // grid-stride fill blocks (237+19 = 256)
#define NEG_SLOPE 0.2f
#define NSB   20             // scan blocks = ceil(NN/1024)
#define PCH   32             // pool chunks per graph

// histconv block ranges
#define HB    704            // hist blocks = ceil(EL/256)
#define XB    13272          // convert_x blocks = MP1*168/256
#define WB    4800           // convert_w blocks

typedef __bf16 bf16x8 __attribute__((ext_vector_type(8)));
typedef __bf16 bf16x4 __attribute__((ext_vector_type(4)));
typedef float  f32x4  __attribute__((ext_vector_type(4)));

__device__ __forceinline__ void gload16(const void* g, void* l) {
    __builtin_amdgcn_global_load_lds(
        (const __attribute__((address_space(1))) void*)g,
        (__attribute__((address_space(3))) void*)l, 16, 0, 0);
}

#define BAR()  { __builtin_amdgcn_s_barrier(); asm volatile("" ::: "memory"); }
#define VMW(n) { asm volatile("s_waitcnt vmcnt(" #n ")" ::: "memory"); __builtin_amdgcn_sched_barrier(0); }

// ---------------- zero small buffers (es2, ed2, deg, cur, scan incl/flag) ----------------
__global__ __launch_bounds__(256)
void zero_kernel(uint4* __restrict__ p, int n16) {
    int i = blockIdx.x * 256 + threadIdx.x;
    if (i < n16) p[i] = (uint4){0u, 0u, 0u, 0u};
}

// ---------------- merged hist + convert x + convert weights ----------------
__global__ __launch_bounds__(256)
void histconv_kernel(const int* __restrict__ ei, int* __restrict__ deg,
                     const float* __restrict__ X, __hip_bfloat16* __restrict__ Xb,
                     const float* __restrict__ W1, const float* __restrict__ W2,
                     __hip_bfloat16* __restrict__ w1t, __hip_bfloat16* __restrict__ w2t) {
    const int b = blockIdx.x, t = threadIdx.x;
    if (b < HB) {
        int e = b * 256 + t;
        if (e < EL) {
            int d = (e < E0) ? ei[E0 + e] : (e - E0);
            atomicAdd(&deg[d], 1);
        }
        return;
    }
    if (b < HB + XB) {
        int idx = (b - HB) * 256 + t;
        const int nb = K1P / 8;   // 168
        int row = idx / nb;
        int cb = (idx - row * nb) * 8;
        union { __hip_bfloat16 h[8]; float4 f4; } u;
        if (row < NN && cb + 8 <= INDIM) {
            const float4* p = (const float4*)(X + (size_t)row * INDIM + cb);
            float4 u0 = p[0], u1 = p[1];
            u.h[0] = __float2bfloat16(u0.x); u.h[1] = __float2bfloat16(u0.y);
            u.h[2] = __float2bfloat16(u0.z); u.h[3] = __float2bfloat16(u0.w);
            u.h[4] = __float2bfloat16(u1.x); u.h[5] = __float2bfloat16(u1.y);
            u.h[6] = __float2bfloat16(u1.z); u.h[7] = __float2bfloat16(u1.w);
        } else {
#pragma unroll
            for (int e = 0; e < 8; e++) {
                float f = (row < NN && cb + e < INDIM) ? X[(size_t)row * INDIM + cb + e] : 0.f;
                u.h[e] = __float2bfloat16(f);
            }
        }
        *(float4*)(Xb + (size_t)row * K1P + cb) = u.f4;
        return;
    }
    {
        int idx = (b - HB - XB) * 256 + t;
        const int n1 = 768 * K1P;
        if (idx < n1) {
            int n = idx / K1P, k = idx - n * K1P;
            float f = (k < INDIM) ? W1[(size_t)k * 768 + n] : 0.f;
            w1t[idx] = __float2bfloat16(f);
        } else {
            int i2 = idx - n1;
            if (i2 < 256 * 768) {
                int n = i2 / 768, k = i2 - n * 768;
                w2t[i2] = __float2bfloat16(W2[(size_t)k * 256 + n]);
            }
        }
    }
}

// ---------------- single-launch scan with serial lookback (20 co-resident blocks) ----------------
__global__ __launch_bounds__(1024)
void scan_one(const int* __restrict__ deg, int* __restrict__ off,
              int* __restrict__ incl, int* __restrict__ flag) {
    __shared__ int wsum[16];
    __shared__ int prevbase;
    const int b = blockIdx.x, t = threadIdx.x, lane = t & 63, wv = t >> 6;
    const int i = b * 1024 + t;
    int v = (i < NN) ? deg[i] : 0;
    int x = v;
#pragma unroll
    for (int o = 1; o < 64; o <<= 1) {
        int y = __shfl_up(x, o, 64);
        if (lane >= o) x += y;
    }
    if (lane == 63) wsum[wv] = x;
    __syncthreads();
    if (wv == 0 && lane < 16) {
        int s = wsum[lane];
#pragma unroll
        for (int o = 1; o < 16; o <<= 1) {
            int y = __shfl_up(s, o, 64);
            if (lane >= o) s += y;
        }
        wsum[lane] = s;
    }
    __syncthreads();
    int woff = (wv == 0) ? 0 : wsum[wv - 1];
    if (t == 0) {
        int p = 0;
        if (b > 0) {
            while (__hip_atomic_load(&flag[b - 1], __ATOMIC_ACQUIRE, __HIP_MEMORY_SCOPE_AGENT) == 0) {}
            p = __hip_atomic_load(&incl[b - 1], __ATOMIC_ACQUIRE, __HIP_MEMORY_SCOPE_AGENT);
        }
        __hip_atomic_store(&incl[b], p + wsum[15], __ATOMIC_RELEASE, __HIP_MEMORY_SCOPE_AGENT);
        __hip_atomic_store(&flag[b], 1, __ATOMIC_RELEASE, __HIP_MEMORY_SCOPE_AGENT);
        prevbase = p;
    }
    __syncthreads();
    if (i < NN) off[i + 1] = prevbase + woff + x;
    if (b == 0 && t == 0) off[0] = 0;
}

// stage one 16-KB A piece (mh): rows {mh*64..+63, 128+mh*64..}; 2 loads/thread
__device__ __forceinline__ void stA(const __hip_bfloat16* __restrict__ A, int bm, int kt, int mh,
                                    char* abuf, int w, int l) {
#pragma unroll
    for (int u = 0; u < 2; u++) {
        int rl = (w << 3) + (l >> 3);            // row_local 0..63
        int lrow = u * 128 + mh * 64 + rl;       // row in 256-row tile
        int skb = ((l & 7) << 4) ^ ((rl & 7) << 4);
        const char* g = (const char*)(A + (size_t)(bm + lrow) * K1P + kt * 64) + skb;
        gload16(g, abuf + (u * 128 + mh * 64) * 128 + (w << 10));
    }
}

// stage one 16-KB B piece (nh): rows with (r&63)>>5 == nh; 2 loads/thread
__device__ __forceinline__ void stB(const __hip_bfloat16* __restrict__ Bt, int bn, int kt, int nh,
                                    char* bbuf, int w, int l) {
#pragma unroll
    for (int u = 0; u < 2; u++) {
        int c = u * 2 + (w >> 2);
        int row0 = c * 64 + nh * 32;
        int rl = ((w & 3) << 3) + (l >> 3);      // 0..31
        int skb = ((l & 7) << 4) ^ ((rl & 7) << 4);
        const char* g = (const char*)(Bt + (size_t)(bn + row0 + rl) * K1P + kt * 64) + skb;
        gload16(g, bbuf + row0 * 128 + ((w & 3) << 10));
    }
}

// ---------------- 256x256 bf16 MFMA GEMM, single-buffer 3-barrier schedule ----------------
__global__ __launch_bounds__(512)
void gemm256(const __hip_bfloat16* __restrict__ A,
             const __hip_bfloat16* __restrict__ Bt,
             __hip_bfloat16* __restrict__ C,
             const float* __restrict__ a_src, const float* __restrict__ a_dst,
             float* __restrict__ esrc, float* __restrict__ edst, int M,
             const int* __restrict__ ei, const int* __restrict__ off,
             int* __restrict__ cur, int* __restrict__ csr) {
    __shared__ char lds[65536];   // A @ 0 (32KB), B @ 32768 (32KB)
    const int t = threadIdx.x;

    // ---- CSR fill tail: 19 grid-stride blocks ----
    if (blockIdx.x >= NWG1) {
        for (int e = (blockIdx.x - NWG1) * 512 + t; e < EL; e += FB * 512) {
            int d = (e < E0) ? ei[E0 + e] : (e - E0);
            int s = (e < E0) ? ei[e] : (e - E0);
            int pos = off[d] + atomicAdd(&cur[d], 1);
            csr[pos] = s;
        }
        return;
    }

    const int w = t >> 6, l = t & 63;
    const int wm = w >> 2, wn = w & 3;           // 2 x 4 waves, each 128x64 output
    const int fr = l & 15, fq = l >> 4;
    const int amask = (fr & 7) << 4;

    const int nwg = NWG1;
    const int q8 = nwg >> 3, r8 = nwg & 7;
    const int xcd = blockIdx.x & 7, sub = blockIdx.x >> 3;
    const int logical = (xcd < r8 ? xcd * (q8 + 1) : r8 * (q8 + 1) + (xcd - r8) * q8) + sub;
    const int bm = (logical / GNX) * 256;
    const int bn = (logical % GNX) * 256;

    f32x4 acc[8][4];
#pragma unroll
    for (int i = 0; i < 8; i++)
#pragma unroll
        for (int j = 0; j < 4; j++) acc[i][j] = (f32x4){0.f, 0.f, 0.f, 0.f};

    char* Ab = lds;
    char* Bb = lds + 32768;

    // prologue: stage tile 0 pieces in completion order PA0, PB0, PB1, PA1
    stA(A, bm, 0, 0, Ab, w, l);
    stB(Bt, bn, 0, 0, Bb, w, l);
    stB(Bt, bn, 0, 1, Bb, w, l);
    stA(A, bm, 0, 1, Ab, w, l);

    for (int kt = 0; kt < GNT; kt++) {
        const bool nl = (kt + 1 < GNT);
        bf16x8 a_c[4][2], b_c0[2][2], b_c1[2][2];

        // ---- q0 ----
        VMW(4);
        BAR();
#pragma unroll
        for (int im = 0; im < 4; im++)
#pragma unroll
            for (int kk = 0; kk < 2; kk++)
                a_c[im][kk] = *(const bf16x8*)(Ab + (wm * 128 + im * 16 + fr) * 128 + ((kk * 64 + fq * 16) ^ amask));
#pragma unroll
        for (int jn = 0; jn < 2; jn++)
#pragma unroll
            for (int kk = 0; kk < 2; kk++)
                b_c0[jn][kk] = *(const bf16x8*)(Bb + (wn * 64 + jn * 16 + fr) * 128 + ((kk * 64 + fq * 16) ^ amask));
        if (nl) stA(A, bm, kt + 1, 0, Ab, w, l);
        __builtin_amdgcn_s_setprio(1);
#pragma unroll
        for (int im = 0; im < 4; im++)
#pragma unroll
            for (int jn = 0; jn < 2; jn++)
#pragma unroll
                for (int kk = 0; kk < 2; kk++)
                    acc[im][jn] = __builtin_amdgcn_mfma_f32_16x16x32_bf16(a_c[im][kk], b_c0[jn][kk], acc[im][jn], 0, 0, 0);
        __builtin_amdgcn_s_setprio(0);

        // ---- q1 ----
        if (nl) { VMW(4); } else { VMW(2); }
        BAR();
#pragma unroll
        for (int jn = 0; jn < 2; jn++)
#pragma unroll
            for (int kk = 0; kk < 2; kk++)
                b_c1[jn][kk] = *(const bf16x8*)(Bb + (wn * 64 + 32 + jn * 16 + fr) * 128 + ((kk * 64 + fq * 16) ^ amask));
        if (nl) stB(Bt, bn, kt + 1, 0, Bb, w, l);
        __builtin_amdgcn_s_setprio(1);
#pragma unroll
        for (int im = 0; im < 4; im++)
#pragma unroll
            for (int jn = 0; jn < 2; jn++)
#pragma unroll
                for (int kk = 0; kk < 2; kk++)
                    acc[im][2 + jn] = __builtin_amdgcn_mfma_f32_16x16x32_bf16(a_c[im][kk], b_c1[jn][kk], acc[im][2 + jn], 0, 0, 0);
        __builtin_amdgcn_s_setprio(0);

        // ---- q2 ----
        if (nl) { VMW(4); } else { VMW(0); }
        BAR();
#pragma unroll
        for (int im = 0; im < 4; im++)
#pragma unroll
            for (int kk = 0; kk < 2; kk++)
                a_c[im][kk] = *(const bf16x8*)(Ab + (wm * 128 + 64 + im * 16 + fr) * 128 + ((kk * 64 + fq * 16) ^ amask));
        if (nl) stB(Bt, bn, kt + 1, 1, Bb, w, l);
        __builtin_amdgcn_s_setprio(1);
#pragma unroll
        for (int im = 0; im < 4; im++)
#pragma unroll
            for (int jn = 0; jn < 2; jn++)
#pragma unroll
                for (int kk = 0; kk < 2; kk++)
                    acc[4 + im][jn] = __builtin_amdgcn_mfma_f32_16x16x32_bf16(a_c[im][kk], b_c0[jn][kk], acc[4 + im][jn], 0, 0, 0);
        __builtin_amdgcn_s_setprio(0);

        // ---- q3 ----
        if (nl) stA(A, bm, kt + 1, 1, Ab, w, l);
        __builtin_amdgcn_s_setprio(1);
#pragma unroll
        for (int im = 0; im < 4; im++)
#pragma unroll
            for (int jn = 0; jn < 2; jn++)
#pragma unroll
                for (int kk = 0; kk < 2; kk++)
                    acc[4 + im][2 + jn] = __builtin_amdgcn_mfma_f32_16x16x32_bf16(a_c[im][kk], b_c1[jn][kk], acc[4 + im][2 + jn], 0, 0, 0);
        __builtin_amdgcn_s_setprio(0);
    }

    // C-write: col=lane&15, row=(lane>>4)*4+reg
#pragma unroll
    for (int i = 0; i < 8; i++)
#pragma unroll
        for (int j = 0; j < 4; j++)
#pragma unroll
            for (int r = 0; r < 4; r++) {
                int row = bm + wm * 128 + i * 16 + fq * 4 + r;
                int col = bn + wn * 64 + j * 16 + fr;
                if (row < M) C[(size_t)row * 768 + col] = __float2bfloat16(acc[i][j][r]);
            }

    // ---- fused e_src/e_dst (this block owns ALL channels of head bn/256) ----
    const int head = bn >> 8;
    float asv[4], adv[4];
#pragma unroll
    for (int j = 0; j < 4; j++) {
        asv[j] = a_src[head * 256 + wn * 64 + j * 16 + fr];
        adv[j] = a_dst[head * 256 + wn * 64 + j * 16 + fr];
    }
    __syncthreads();                     // done with MFMA lds; reuse as [256][4][2] f32
    float* eb = (float*)lds;
#pragma unroll
    for (int i = 0; i < 8; i++) {
#pragma unroll
        for (int r = 0; r < 4; r++) {
            float ps = 0.f, pd = 0.f;
#pragma unroll
            for (int j = 0; j < 4; j++) { ps += acc[i][j][r] * asv[j]; pd += acc[i][j][r] * adv[j]; }
#pragma unroll
            for (int o = 8; o >= 1; o >>= 1) { ps += __shfl_xor(ps, o, 64); pd += __shfl_xor(pd, o, 64); }
            if (fr == 0) {
                int rowl = wm * 128 + i * 16 + fq * 4 + r;
                eb[(rowl * 4 + wn) * 2 + 0] = ps;
                eb[(rowl * 4 + wn) * 2 + 1] = pd;
            }
        }
    }
    __syncthreads();
    if (t < 256) {
        int row = bm + t;
        if (row < M) {
            float s = eb[t * 8 + 0] + eb[t * 8 + 2] + eb[t * 8 + 4] + eb[t * 8 + 6];
            float d = eb[t * 8 + 1] + eb[t * 8 + 3] + eb[t * 8 + 5] + eb[t * 8 + 7];
            esrc[row * 3 + head] = s;
            edst[row * 3 + head] = d;
        }
    }
}

// ---------------- 2-phase double-buffered 128x128 GEMM (GEMM2) + fused layer-2 e ----------------
__global__ __launch_bounds__(256)
void gemm2_fused(const __hip_bfloat16* __restrict__ A,
                 const __hip_bfloat16* __restrict__ Bt,
                 __hip_bfloat16* __restrict__ C,
                 const float* __restrict__ a_src2, const float* __restrict__ a_dst2,
                 float* __restrict__ esrc, float* __restrict__ edst,
                 int M, int N, int K, int NX) {
    __shared__ __hip_bfloat16 As[2][128 * 32];
    __shared__ __hip_bfloat16 Bs[2][128 * 32];
    const int t = threadIdx.x;
    const int w = t >> 6;
    const int l = t & 63;

    const int nwg = gridDim.x;
    const int q = nwg >> 3, r = nwg & 7;
    const int xcd = blockIdx.x & 7, idx = blockIdx.x >> 3;
    const int logical = (xcd < r ? xcd * (q + 1) : r * (q + 1) + (xcd - r) * q) + idx;
    const int bm = (logical / NX) * 128;
    const int bn = (logical % NX) * 128;

    const int wm = (w >> 1) * 64;
    const int wn = (w & 1) * 64;

    f32x4 acc[4][4];
#pragma unroll
    for (int i = 0; i < 4; i++)
#pragma unroll
        for (int j = 0; j < 4; j++) acc[i][j] = (f32x4){0.f, 0.f, 0.f, 0.f};

    const int sr = t >> 2;
    const int sc = (t & 3) * 8;
    const __hip_bfloat16* a0 = A  + (size_t)(bm + sr)      * K + sc;
    const __hip_bfloat16* a1 = A  + (size_t)(bm + 64 + sr) * K + sc;
    const __hip_bfloat16* b0 = Bt + (size_t)(bn + sr)      * K + sc;
    const __hip_bfloat16* b1 = Bt + (size_t)(bn + 64 + sr) * K + sc;

    const int fr = l & 15;
    const int fq = l >> 4;
    const int NT = K / 32;

    auto stage = [&](int k0, int b) {
        char* asb = (char*)&As[b][0];
        char* bsb = (char*)&Bs[b][0];
        gload16(a0 + k0, asb + w * 1024);
        gload16(a1 + k0, asb + 4096 + w * 1024);
        gload16(b0 + k0, bsb + w * 1024);
        gload16(b1 + k0, bsb + 4096 + w * 1024);
    };

    stage(0, 0);
    __syncthreads();

    for (int kt = 0; kt < NT; kt++) {
        const int cb = kt & 1;
        if (kt + 1 < NT) stage((kt + 1) * 32, cb ^ 1);
        bf16x8 av[4], bv[4];
#pragma unroll
        for (int i = 0; i < 4; i++)
            av[i] = *(const bf16x8*)&As[cb][(wm + i * 16 + fr) * 32 + fq * 8];
#pragma unroll
        for (int j = 0; j < 4; j++)
            bv[j] = *(const bf16x8*)&Bs[cb][(wn + j * 16 + fr) * 32 + fq * 8];
#pragma unroll
        for (int i = 0; i < 4; i++)
#pragma unroll
            for (int j = 0; j < 4; j++)
                acc[i][j] = __builtin_amdgcn_mfma_f32_16x16x32_bf16(av[i], bv[j], acc[i][j], 0, 0, 0);
        __syncthreads();
    }

#pragma unroll
    for (int i = 0; i < 4; i++) {
#pragma unroll
        for (int j = 0; j < 4; j++) {
#pragma unroll
            for (int r2 = 0; r2 < 4; r2++) {
                int row = bm + wm + i * 16 + fq * 4 + r2;
                int col = bn + wn + j * 16 + fr;
                if (row < M) C[(size_t)row * N + col] = __float2bfloat16(acc[i][j][r2]);
            }
        }
    }

    // ---- fused layer-2 e partials ----
    float asv[4], adv[4];
#pragma unroll
    for (int j = 0; j < 4; j++) {
        asv[j] = a_src2[bn + wn + j * 16 + fr];
        adv[j] = a_dst2[bn + wn + j * 16 + fr];
    }
    __syncthreads();
    float* eb = (float*)&As[0][0];
#pragma unroll
    for (int i = 0; i < 4; i++) {
#pragma unroll
        for (int r2 = 0; r2 < 4; r2++) {
            float ps = 0.f, pd = 0.f;
#pragma unroll
            for (int j = 0; j < 4; j++) { ps += acc[i][j][r2] * asv[j]; pd += acc[i][j][r2] * adv[j]; }
#pragma unroll
            for (int o = 8; o >= 1; o >>= 1) { ps += __shfl_xor(ps, o, 64); pd += __shfl_xor(pd, o, 64); }
            if (fr == 0) {
                int rowl = wm + i * 16 + fq * 4 + r2;
                int wnIdx = wn >> 6;
                eb[(rowl * 2 + wnIdx) * 2 + 0] = ps;
                eb[(rowl * 2 + wnIdx) * 2 + 1] = pd;
            }
        }
    }
    __syncthreads();
    if (t < 128) {
        int row = bm + t;
        if (row < M) {
            atomicAdd(&esrc[row], eb[t * 4 + 0] + eb[t * 4 + 2]);
            atomicAdd(&edst[row], eb[t * 4 + 1] + eb[t * 4 + 3]);
        }
    }
}

// ---------------- GAT aggregation: one WAVE per (node, head) pair ----------------
template<int H, bool RELU, typename OutT>
__global__ __launch_bounds__(256)
void gat_aggregate(const __hip_bfloat16* __restrict__ hfeat,
                   const float* __restrict__ esrc,
                   const float* __restrict__ edst,
                   const int* __restrict__ off, const int* __restrict__ csr,
                   const float* __restrict__ bias,
                   OutT* __restrict__ out, int N) {
    const int wv = threadIdx.x >> 6, lane = threadIdx.x & 63;
    const int pair = blockIdx.x * 4 + wv;
    if (pair >= N * H) return;
    const int n = pair / H;
    const int h = pair - n * H;
    const int beg = off[n];
    const int deg = off[n + 1] - beg;

    const float ed = edst[n * H + h];
    float m = -INFINITY, den = 0.f;
    f32x4 acc = (f32x4){0.f, 0.f, 0.f, 0.f};

    for (int base = 0; base < deg; base += 64) {
        const int i = base + lane;
        int s = 0;
        float lg = -INFINITY;
        if (i < deg) {
            s = csr[beg + i];
            float v = esrc[s * H + h] + ed;
            lg = (v >= 0.f) ? v : NEG_SLOPE * v;
        }
        float cm = lg;
#pragma unroll
        for (int o = 1; o < 64; o <<= 1)
            cm = fmaxf(cm, __shfl_xor(cm, o, 64));
        float nm = fmaxf(m, cm);
        float sc = expf(m - nm);
        den *= sc;
#pragma unroll
        for (int e = 0; e < 4; e++) acc[e] *= sc;
        m = nm;
        float wgt = (i < deg) ? expf(lg - m) : 0.f;
        den += wgt;
        const int cnt = min(64, deg - base);
        for (int j = 0; j < cnt; j++) {
            int sj = __shfl(s, j, 64);
            float wj = __shfl(wgt, j, 64);
            bf16x4 hv = *(const bf16x4*)(hfeat + (size_t)sj * (H * 256) + h * 256 + 4 * lane);
#pragma unroll
            for (int e = 0; e < 4; e++) acc[e] += wj * (float)hv[e];
        }
    }
#pragma unroll
    for (int o = 1; o < 64; o <<= 1) den += __shfl_xor(den, o, 64);

    float inv = 1.f / (den + 1e-16f);
    if constexpr (sizeof(OutT) == 2) {
        bf16x4 r;
#pragma unroll
        for (int e = 0; e < 4; e++) {
            float f = acc[e] * inv + bias[h * 256 + 4 * lane + e];
            if (RELU) f = fmaxf(f, 0.f);
            r[e] = (__bf16)f;
        }
        *(bf16x4*)((__hip_bfloat16*)out + (size_t)n * (H * 256) + h * 256 + 4 * lane) = r;
    } else {
        float4 r;
        float* rp = &r.x;
#pragma unroll
        for (int e = 0; e < 4; e++) {
            float f = acc[e] * inv + bias[h * 256 + 4 * lane + e];
            if (RELU) f = fmaxf(f, 0.f);
            rp[e] = f;
        }
        *(float4*)((float*)out + (size_t)n * (H * 256) + h * 256 + 4 * lane) = r;
    }
}

// ---------------- pooling: high-parallelism partial sums (2048 blocks, 4-way ILP) ----------------
__device__ __forceinline__ int lower_bound_batch(const int* __restrict__ batch, int key) {
    int lo = 0, hi = NN;
    while (lo < hi) {
        int mid = (lo + hi) >> 1;
        if (batch[mid] < key) lo = mid + 1; else hi = mid;
    }
    return lo;
}

__global__ __launch_bounds__(256)
void pool_partial(const __hip_bfloat16* __restrict__ out2, const int* __restrict__ batch,
                  float* __restrict__ partial, float* __restrict__ cnts) {
    const int g = blockIdx.x, c = blockIdx.y, t = threadIdx.x;
    const int s = lower_bound_batch(batch, g);
    const int e = lower_bound_batch(batch, g + 1);
    float a0 = 0.f, a1 = 0.f, a2 = 0.f, a3 = 0.f;
    int n = s + c;
    for (; n + 3 * PCH < e; n += 4 * PCH) {
        float v0 = __bfloat162float(out2[(size_t)n * 256 + t]);
        float v1 = __bfloat162float(out2[(size_t)(n + PCH) * 256 + t]);
        float v2 = __bfloat162float(out2[(size_t)(n + 2 * PCH) * 256 + t]);
        float v3 = __bfloat162float(out2[(size_t)(n + 3 * PCH) * 256 + t]);
        a0 += v0; a1 += v1; a2 += v2; a3 += v3;
    }
    for (; n < e; n += PCH) a0 += __bfloat162float(out2[(size_t)n * 256 + t]);
    partial[((size_t)g * PCH + c) * 256 + t] = a0 + a1 + a2 + a3;
    if (t == 0 && c == 0) cnts[g] = (float)(e - s);
}

// ---------------- MLP head + softmax (folds PCH partials) ----------------
__global__ __launch_bounds__(256)
void head_kernel(const float* __restrict__ partial, const float* __restrict__ cnts,
                 const float* __restrict__ phy,
                 const float* __restrict__ w11, const float* __restrict__ b11,
                 const float* __restrict__ w12, const float* __restrict__ b12,
                 const float* __restrict__ w21, const float* __restrict__ b21,
                 const float* __restrict__ w22, const float* __restrict__ b22,
                 float* __restrict__ out) {
    int g = blockIdx.x, t = threadIdx.x;
    __shared__ float ph[188];
    __shared__ float z[384];
    __shared__ float mid[128];
    __shared__ float t1[192];
    __shared__ float lg[2];
    if (t < 188) ph[t] = phy[g * 188 + t];
    {
        float s = 0.f;
#pragma unroll
        for (int c = 0; c < PCH; c++) s += partial[((size_t)g * PCH + c) * 256 + t];
        z[t] = s / fmaxf(cnts[g], 1.0f);
    }
    __syncthreads();
    if (t < 128) {
        float sm = b11[t];
        for (int k = 0; k < 188; k++) sm += ph[k] * w11[k * 128 + t];
        mid[t] = fmaxf(sm, 0.f);
    }
    __syncthreads();
    if (t < 128) {
        float sm = b12[t];
        for (int k = 0; k < 128; k++) sm += mid[k] * w12[k * 128 + t];
        z[256 + t] = fmaxf(sm, 0.f);
    }
    __syncthreads();
    if (t < 192) {
        float sm = b21[t];
        for (int k = 0; k < 384; k++) sm += z[k] * w21[k * 192 + t];
        t1[t] = fmaxf(sm, 0.f);
    }
    __syncthreads();
    if (t < 2) {
        float sm = b22[t];
        for (int k = 0; k < 192; k++) sm += t1[k] * w22[k * 2 + t];
        lg[t] = sm;
    }
    __syncthreads();
    if (t == 0) {
        float mx = fmaxf(lg[0], lg[1]);
        float e0 = expf(lg[0] - mx), e1 = expf(lg[1] - mx);
        float d = e0 + e1;
        out[g * 2 + 0] = e0 / d;
        out[g * 2 + 1] = e1 / d;
    }
}

extern "C" void kernel_launch(void* const* d_in, const int* in_sizes, int n_in,
                              void* d_out, int out_size, void* d_ws, size_t ws_size,
                              hipStream_t stream) {
    const float* x       = (const float*)d_in[0];
    const int*   ei      = (const int*)  d_in[1];
    const float* phy     = (const float*)d_in[2];
    const int*   batch   = (const int*)  d_in[3];
    const float* W1      = (const float*)d_in[4];
    const float* a_src1  = (const float*)d_in[5];
    const float* a_dst1  = (const float*)d_in[6];
    const float* b1      = (const float*)d_in[7];
    const float* W2      = (const float*)d_in[8];
    const float* a_src2  = (const float*)d_in[9];
    const float* a_dst2  = (const float*)d_in[10];
    const float* b2      = (const float*)d_in[11];
    const float* fc1_w1  = (const float*)d_in[12];
    const float* fc1_b1  = (const float*)d_in[13];
    const float* fc1_w2  = (const float*)d_in[14];
    const float* fc1_b2  = (const float*)d_in[15];
    const float* fc2_w1  = (const float*)d_in[16];
    const float* fc2_b1  = (const float*)d_in[17];
    const float* fc2_w2  = (const float*)d_in[18];
    const float* fc2_b2  = (const float*)d_in[19];
    float* out = (float*)d_out;

    char* base = (char*)d_ws;
    size_t o = 0;
    auto alloc = [&](size_t bytes) { size_t r = o; o += (bytes + 255) & ~255ULL; return r; };

    size_t o_xb   = alloc((size_t)MP1 * K1P * 2);    // reused for h2b/out2 after GEMM1
    size_t o_w1t  = alloc((size_t)768 * K1P * 2);
    size_t o_w2t  = alloc((size_t)256 * 768 * 2);
    size_t o_h1b  = alloc((size_t)NP * 768 * 2);
    size_t o_hob  = alloc((size_t)NP * 768 * 2);
    size_t o_es1  = alloc((size_t)NN * 3 * 4);
    size_t o_ed1  = alloc((size_t)NN * 3 * 4);
    // zero region: es2, ed2, deg, cur, incl, flag contiguous
    size_t o_es2  = alloc((size_t)NN * 4);
    size_t o_ed2  = alloc((size_t)NN * 4);
    size_t o_deg  = alloc((size_t)(NN + 1) * 4);
    size_t o_cur  = alloc((size_t)NN * 4);
    size_t o_incl = alloc((size_t)NSB * 4);
    size_t o_flag = alloc((size_t)NSB * 4);
    size_t o_zend = o;
    size_t o_off  = alloc((size_t)(NN + 1) * 4);
    size_t o_csr  = alloc((size_t)EL * 4);
    size_t o_part = alloc((size_t)NG * PCH * 256 * 4);
    size_t o_cnts = alloc((size_t)NG * 4);

    __hip_bfloat16* xb   = (__hip_bfloat16*)(base + o_xb);
    __hip_bfloat16* w1t  = (__hip_bfloat16*)(base + o_w1t);
    __hip_bfloat16* w2t  = (__hip_bfloat16*)(base + o_w2t);
    __hip_bfloat16* h1b  = (__hip_bfloat16*)(base + o_h1b);
    __hip_bfloat16* hob  = (__hip_bfloat16*)(base + o_hob);
    __hip_bfloat16* h2b  = (__hip_bfloat16*)(base + o_xb);
    __hip_bfloat16* out2 = (__hip_bfloat16*)(base + o_xb + (size_t)24 * 1024 * 1024);
    float* es1   = (float*)(base + o_es1);
    float* ed1   = (float*)(base + o_ed1);
    float* es2   = (float*)(base + o_es2);
    float* ed2   = (float*)(base + o_ed2);
    int*   deg   = (int*)(base + o_deg);
    int*   cur   = (int*)(base + o_cur);
    int*   incl  = (int*)(base + o_incl);
    int*   flag  = (int*)(base + o_flag);
    int*   offs  = (int*)(base + o_off);
    int*   csr   = (int*)(base + o_csr);
    float* part  = (float*)(base + o_part);
    float* cnts  = (float*)(base + o_cnts);

    // 1) zero small state (es2, ed2, deg, cur, incl, flag)
    {
        int n16 = (int)((o_zend - o_es2) / 16);
        zero_kernel<<<(n16 + 255) / 256, 256, 0, stream>>>((uint4*)(base + o_es2), n16);
    }
    // 2) hist (hidden under the BW-bound conversions) + convert x + convert weights
    histconv_kernel<<<HB + XB + WB, 256, 0, stream>>>(ei, deg, x, xb, W1, W2, w1t, w2t);
    // 3) single-launch chained scan
    scan_one<<<NSB, 1024, 0, stream>>>(deg, offs, incl, flag);

    // 4) gemm1 (+fused layer-1 e, + CSR fill tail)
    gemm256<<<NWG1 + FB, 512, 0, stream>>>(xb, w1t, h1b, a_src1, a_dst1, es1, ed1, NN,
                                           ei, offs, cur, csr);
    gat_aggregate<3, true, __hip_bfloat16><<<(NN * 3 + 3) / 4, 256, 0, stream>>>(h1b, es1, ed1, offs, csr, b1, hob, NN);

    gemm2_fused<<<2 * 157, 256, 0, stream>>>(hob, w2t, h2b, a_src2, a_dst2, es2, ed2, NN, 256, 768, 2);
    gat_aggregate<1, false, __hip_bfloat16><<<(NN + 3) / 4, 256, 0, stream>>>(h2b, es2, ed2, offs, csr, b2, out2, NN);

    pool_partial<<<dim3(NG, PCH), 256, 0, stream>>>(out2, batch, part, cnts);
    head_kernel<<<NG, 256, 0, stream>>>(part, cnts, phy,
                                        fc1_w1, fc1_b1, fc1_w2, fc1_b2,
                                        fc2_w1, fc2_b1, fc2_w2, fc2_b2, out);
}

// Round 14
// 230.312 us; speedup vs baseline: 1.1095x; 1.1095x over previous
//
#include <hip/hip_runtime.h>
#include <hip/hip_bf16.h>
#include <math.h>

#define NN    20000
#define MP1   20224          // 79*256 padded rows for gemm1
#define NP    20096          // 157*128 padded rows for gemm2 A
#define E0    160000
#define EL    180000
#define NG    64
#define INDIM 1304
#define K1P   1344           // K padded to multiple of 64 (21 K-tiles)
#define GNT   21             // K1P/64
#define GNX   3              // 768/256
#define GMB   79             // M blocks
#define NWG1  (GMB * GNX)    // 237 gemm blocks
#define FB    19             // grid-stride fill blocks (237+19 = 256)
#define NEG_SLOPE 0.2f
#define NSB   20             // scan blocks = ceil(NN/1024)
#define PCH   32             // pool chunks per graph

// init_kernel block ranges
#define ZB    80             // zero blocks (es2+ed2+deg+cur ~320KB)
#define XB    13272          // convert_x blocks = MP1*168/256
#define WB    4800           // convert_w blocks

typedef __bf16 bf16x8 __attribute__((ext_vector_type(8)));
typedef __bf16 bf16x4 __attribute__((ext_vector_type(4)));
typedef float  f32x4  __attribute__((ext_vector_type(4)));

__device__ __forceinline__ void gload16(const void* g, void* l) {
    __builtin_amdgcn_global_load_lds(
        (const __attribute__((address_space(1))) void*)g,
        (__attribute__((address_space(3))) void*)l, 16, 0, 0);
}

#define BAR()  { __builtin_amdgcn_s_barrier(); asm volatile("" ::: "memory"); }
#define VMW(n) { asm volatile("s_waitcnt vmcnt(" #n ")" ::: "memory"); __builtin_amdgcn_sched_barrier(0); }

// ---------------- merged init: zero small buffers + convert x + convert weights ----------------
__global__ __launch_bounds__(256)
void init_kernel(uint4* __restrict__ zreg, int n16,
                 const float* __restrict__ X, __hip_bfloat16* __restrict__ Xb,
                 const float* __restrict__ W1, const float* __restrict__ W2,
                 __hip_bfloat16* __restrict__ w1t, __hip_bfloat16* __restrict__ w2t) {
    const int b = blockIdx.x, t = threadIdx.x;
    if (b < ZB) {
        int i = b * 256 + t;
        if (i < n16) zreg[i] = (uint4){0u, 0u, 0u, 0u};
        return;
    }
    if (b < ZB + XB) {
        int idx = (b - ZB) * 256 + t;
        const int nb = K1P / 8;   // 168
        int row = idx / nb;
        int cb = (idx - row * nb) * 8;
        union { __hip_bfloat16 h[8]; float4 f4; } u;
        if (row < NN && cb + 8 <= INDIM) {
            const float4* p = (const float4*)(X + (size_t)row * INDIM + cb);
            float4 u0 = p[0], u1 = p[1];
            u.h[0] = __float2bfloat16(u0.x); u.h[1] = __float2bfloat16(u0.y);
            u.h[2] = __float2bfloat16(u0.z); u.h[3] = __float2bfloat16(u0.w);
            u.h[4] = __float2bfloat16(u1.x); u.h[5] = __float2bfloat16(u1.y);
            u.h[6] = __float2bfloat16(u1.z); u.h[7] = __float2bfloat16(u1.w);
        } else {
#pragma unroll
            for (int e = 0; e < 8; e++) {
                float f = (row < NN && cb + e < INDIM) ? X[(size_t)row * INDIM + cb + e] : 0.f;
                u.h[e] = __float2bfloat16(f);
            }
        }
        *(float4*)(Xb + (size_t)row * K1P + cb) = u.f4;
        return;
    }
    {
        int idx = (b - ZB - XB) * 256 + t;
        const int n1 = 768 * K1P;
        if (idx < n1) {
            int n = idx / K1P, k = idx - n * K1P;
            float f = (k < INDIM) ? W1[(size_t)k * 768 + n] : 0.f;
            w1t[idx] = __float2bfloat16(f);
        } else {
            int i2 = idx - n1;
            if (i2 < 256 * 768) {
                int n = i2 / 768, k = i2 - n * 768;
                w2t[i2] = __float2bfloat16(W2[(size_t)k * 256 + n]);
            }
        }
    }
}

// stage one 16-KB A piece (mh): rows {mh*64..+63, 128+mh*64..}; 2 loads/thread
__device__ __forceinline__ void stA(const __hip_bfloat16* __restrict__ A, int bm, int kt, int mh,
                                    char* abuf, int w, int l) {
#pragma unroll
    for (int u = 0; u < 2; u++) {
        int rl = (w << 3) + (l >> 3);            // row_local 0..63
        int lrow = u * 128 + mh * 64 + rl;       // row in 256-row tile
        int skb = ((l & 7) << 4) ^ ((rl & 7) << 4);
        const char* g = (const char*)(A + (size_t)(bm + lrow) * K1P + kt * 64) + skb;
        gload16(g, abuf + (u * 128 + mh * 64) * 128 + (w << 10));
    }
}

// stage one 16-KB B piece (nh): rows with (r&63)>>5 == nh; 2 loads/thread
__device__ __forceinline__ void stB(const __hip_bfloat16* __restrict__ Bt, int bn, int kt, int nh,
                                    char* bbuf, int w, int l) {
#pragma unroll
    for (int u = 0; u < 2; u++) {
        int c = u * 2 + (w >> 2);
        int row0 = c * 64 + nh * 32;
        int rl = ((w & 3) << 3) + (l >> 3);      // 0..31
        int skb = ((l & 7) << 4) ^ ((rl & 7) << 4);
        const char* g = (const char*)(Bt + (size_t)(bn + row0 + rl) * K1P + kt * 64) + skb;
        gload16(g, bbuf + row0 * 128 + ((w & 3) << 10));
    }
}

// ---------------- 256x256 bf16 MFMA GEMM, single-buffer 3-barrier schedule ----------------
// Row lifetimes: A-low read only in q0, B-nh0 in q0 (cached in regs), B-nh1 in q1,
// A-high in q2 -> each quad stages the piece whose rows it just freed.
// Piece order PA0,PB0,PB1,PA1 => uniform VMW(4) per quad, 3 barriers/K-tile.
__global__ __launch_bounds__(512)
void gemm256(const __hip_bfloat16* __restrict__ A,
             const __hip_bfloat16* __restrict__ Bt,
             __hip_bfloat16* __restrict__ C,
             const float* __restrict__ a_src, const float* __restrict__ a_dst,
             float* __restrict__ esrc, float* __restrict__ edst, int M,
             const int* __restrict__ ei, const int* __restrict__ off,
             int* __restrict__ cur, int* __restrict__ csr) {
    __shared__ char lds[65536];   // A @ 0 (32KB), B @ 32768 (32KB)
    const int t = threadIdx.x;

    // ---- CSR fill tail: 19 grid-stride blocks ----
    if (blockIdx.x >= NWG1) {
        for (int e = (blockIdx.x - NWG1) * 512 + t; e < EL; e += FB * 512) {
            int d = (e < E0) ? ei[E0 + e] : (e - E0);
            int s = (e < E0) ? ei[e] : (e - E0);
            int pos = off[d] + atomicAdd(&cur[d], 1);
            csr[pos] = s;
        }
        return;
    }

    const int w = t >> 6, l = t & 63;
    const int wm = w >> 2, wn = w & 3;           // 2 x 4 waves, each 128x64 output
    const int fr = l & 15, fq = l >> 4;
    const int amask = (fr & 7) << 4;

    const int nwg = NWG1;
    const int q8 = nwg >> 3, r8 = nwg & 7;
    const int xcd = blockIdx.x & 7, sub = blockIdx.x >> 3;
    const int logical = (xcd < r8 ? xcd * (q8 + 1) : r8 * (q8 + 1) + (xcd - r8) * q8) + sub;
    const int bm = (logical / GNX) * 256;
    const int bn = (logical % GNX) * 256;

    f32x4 acc[8][4];
#pragma unroll
    for (int i = 0; i < 8; i++)
#pragma unroll
        for (int j = 0; j < 4; j++) acc[i][j] = (f32x4){0.f, 0.f, 0.f, 0.f};

    char* Ab = lds;
    char* Bb = lds + 32768;

    // prologue: stage tile 0 pieces in completion order PA0, PB0, PB1, PA1
    stA(A, bm, 0, 0, Ab, w, l);
    stB(Bt, bn, 0, 0, Bb, w, l);
    stB(Bt, bn, 0, 1, Bb, w, l);
    stA(A, bm, 0, 1, Ab, w, l);

    for (int kt = 0; kt < GNT; kt++) {
        const bool nl = (kt + 1 < GNT);
        bf16x8 a_c[4][2], b_c0[2][2], b_c1[2][2];

        // ---- q0: wait PA0+PB0(kt); read A-low + B-nh0; stage PA0(kt+1); MFMA ----
        VMW(4);
        BAR();
#pragma unroll
        for (int im = 0; im < 4; im++)
#pragma unroll
            for (int kk = 0; kk < 2; kk++)
                a_c[im][kk] = *(const bf16x8*)(Ab + (wm * 128 + im * 16 + fr) * 128 + ((kk * 64 + fq * 16) ^ amask));
#pragma unroll
        for (int jn = 0; jn < 2; jn++)
#pragma unroll
            for (int kk = 0; kk < 2; kk++)
                b_c0[jn][kk] = *(const bf16x8*)(Bb + (wn * 64 + jn * 16 + fr) * 128 + ((kk * 64 + fq * 16) ^ amask));
        if (nl) stA(A, bm, kt + 1, 0, Ab, w, l);
        __builtin_amdgcn_s_setprio(1);
#pragma unroll
        for (int im = 0; im < 4; im++)
#pragma unroll
            for (int jn = 0; jn < 2; jn++)
#pragma unroll
                for (int kk = 0; kk < 2; kk++)
                    acc[im][jn] = __builtin_amdgcn_mfma_f32_16x16x32_bf16(a_c[im][kk], b_c0[jn][kk], acc[im][jn], 0, 0, 0);
        __builtin_amdgcn_s_setprio(0);

        // ---- q1: wait PB1(kt); read B-nh1; stage PB0(kt+1); MFMA ----
        if (nl) { VMW(4); } else { VMW(2); }
        BAR();
#pragma unroll
        for (int jn = 0; jn < 2; jn++)
#pragma unroll
            for (int kk = 0; kk < 2; kk++)
                b_c1[jn][kk] = *(const bf16x8*)(Bb + (wn * 64 + 32 + jn * 16 + fr) * 128 + ((kk * 64 + fq * 16) ^ amask));
        if (nl) stB(Bt, bn, kt + 1, 0, Bb, w, l);
        __builtin_amdgcn_s_setprio(1);
#pragma unroll
        for (int im = 0; im < 4; im++)
#pragma unroll
            for (int jn = 0; jn < 2; jn++)
#pragma unroll
                for (int kk = 0; kk < 2; kk++)
                    acc[im][2 + jn] = __builtin_amdgcn_mfma_f32_16x16x32_bf16(a_c[im][kk], b_c1[jn][kk], acc[im][2 + jn], 0, 0, 0);
        __builtin_amdgcn_s_setprio(0);

        // ---- q2: wait PA1(kt); read A-high; stage PB1(kt+1); MFMA ----
        if (nl) { VMW(4); } else { VMW(0); }
        BAR();
#pragma unroll
        for (int im = 0; im < 4; im++)
#pragma unroll
            for (int kk = 0; kk < 2; kk++)
                a_c[im][kk] = *(const bf16x8*)(Ab + (wm * 128 + 64 + im * 16 + fr) * 128 + ((kk * 64 + fq * 16) ^ amask));
        if (nl) stB(Bt, bn, kt + 1, 1, Bb, w, l);
        __builtin_amdgcn_s_setprio(1);
#pragma unroll
        for (int im = 0; im < 4; im++)
#pragma unroll
            for (int jn = 0; jn < 2; jn++)
#pragma unroll
                for (int kk = 0; kk < 2; kk++)
                    acc[4 + im][jn] = __builtin_amdgcn_mfma_f32_16x16x32_bf16(a_c[im][kk], b_c0[jn][kk], acc[4 + im][jn], 0, 0, 0);
        __builtin_amdgcn_s_setprio(0);

        // ---- q3: no reads (regs cached); stage PA1(kt+1); MFMA ----
        if (nl) stA(A, bm, kt + 1, 1, Ab, w, l);
        __builtin_amdgcn_s_setprio(1);
#pragma unroll
        for (int im = 0; im < 4; im++)
#pragma unroll
            for (int jn = 0; jn < 2; jn++)
#pragma unroll
                for (int kk = 0; kk < 2; kk++)
                    acc[4 + im][2 + jn] = __builtin_amdgcn_mfma_f32_16x16x32_bf16(a_c[im][kk], b_c1[jn][kk], acc[4 + im][2 + jn], 0, 0, 0);
        __builtin_amdgcn_s_setprio(0);
    }

    // C-write: col=lane&15, row=(lane>>4)*4+reg
#pragma unroll
    for (int i = 0; i < 8; i++)
#pragma unroll
        for (int j = 0; j < 4; j++)
#pragma unroll
            for (int r = 0; r < 4; r++) {
                int row = bm + wm * 128 + i * 16 + fq * 4 + r;
                int col = bn + wn * 64 + j * 16 + fr;
                if (row < M) C[(size_t)row * 768 + col] = __float2bfloat16(acc[i][j][r]);
            }

    // ---- fused e_src/e_dst (this block owns ALL channels of head bn/256) ----
    const int head = bn >> 8;
    float asv[4], adv[4];
#pragma unroll
    for (int j = 0; j < 4; j++) {
        asv[j] = a_src[head * 256 + wn * 64 + j * 16 + fr];
        adv[j] = a_dst[head * 256 + wn * 64 + j * 16 + fr];
    }
    __syncthreads();                     // done with MFMA lds; reuse as [256][4][2] f32
    float* eb = (float*)lds;
#pragma unroll
    for (int i = 0; i < 8; i++) {
#pragma unroll
        for (int r = 0; r < 4; r++) {
            float ps = 0.f, pd = 0.f;
#pragma unroll
            for (int j = 0; j < 4; j++) { ps += acc[i][j][r] * asv[j]; pd += acc[i][j][r] * adv[j]; }
#pragma unroll
            for (int o = 8; o >= 1; o >>= 1) { ps += __shfl_xor(ps, o, 64); pd += __shfl_xor(pd, o, 64); }
            if (fr == 0) {
                int rowl = wm * 128 + i * 16 + fq * 4 + r;
                eb[(rowl * 4 + wn) * 2 + 0] = ps;
                eb[(rowl * 4 + wn) * 2 + 1] = pd;
            }
        }
    }
    __syncthreads();
    if (t < 256) {
        int row = bm + t;
        if (row < M) {
            float s = eb[t * 8 + 0] + eb[t * 8 + 2] + eb[t * 8 + 4] + eb[t * 8 + 6];
            float d = eb[t * 8 + 1] + eb[t * 8 + 3] + eb[t * 8 + 5] + eb[t * 8 + 7];
            esrc[row * 3 + head] = s;
            edst[row * 3 + head] = d;
        }
    }
}

// ---------------- 2-phase double-buffered 128x128 GEMM (GEMM2) + fused layer-2 e ----------------
__global__ __launch_bounds__(256)
void gemm2_fused(const __hip_bfloat16* __restrict__ A,
                 const __hip_bfloat16* __restrict__ Bt,
                 __hip_bfloat16* __restrict__ C,
                 const float* __restrict__ a_src2, const float* __restrict__ a_dst2,
                 float* __restrict__ esrc, float* __restrict__ edst,
                 int M, int N, int K, int NX) {
    __shared__ __hip_bfloat16 As[2][128 * 32];
    __shared__ __hip_bfloat16 Bs[2][128 * 32];
    const int t = threadIdx.x;
    const int w = t >> 6;
    const int l = t & 63;

    const int nwg = gridDim.x;
    const int q = nwg >> 3, r = nwg & 7;
    const int xcd = blockIdx.x & 7, idx = blockIdx.x >> 3;
    const int logical = (xcd < r ? xcd * (q + 1) : r * (q + 1) + (xcd - r) * q) + idx;
    const int bm = (logical / NX) * 128;
    const int bn = (logical % NX) * 128;

    const int wm = (w >> 1) * 64;
    const int wn = (w & 1) * 64;

    f32x4 acc[4][4];
#pragma unroll
    for (int i = 0; i < 4; i++)
#pragma unroll
        for (int j = 0; j < 4; j++) acc[i][j] = (f32x4){0.f, 0.f, 0.f, 0.f};

    const int sr = t >> 2;
    const int sc = (t & 3) * 8;
    const __hip_bfloat16* a0 = A  + (size_t)(bm + sr)      * K + sc;
    const __hip_bfloat16* a1 = A  + (size_t)(bm + 64 + sr) * K + sc;
    const __hip_bfloat16* b0 = Bt + (size_t)(bn + sr)      * K + sc;
    const __hip_bfloat16* b1 = Bt + (size_t)(bn + 64 + sr) * K + sc;

    const int fr = l & 15;
    const int fq = l >> 4;
    const int NT = K / 32;

    auto stage = [&](int k0, int b) {
        char* asb = (char*)&As[b][0];
        char* bsb = (char*)&Bs[b][0];
        gload16(a0 + k0, asb + w * 1024);
        gload16(a1 + k0, asb + 4096 + w * 1024);
        gload16(b0 + k0, bsb + w * 1024);
        gload16(b1 + k0, bsb + 4096 + w * 1024);
    };

    stage(0, 0);
    __syncthreads();

    for (int kt = 0; kt < NT; kt++) {
        const int cb = kt & 1;
        if (kt + 1 < NT) stage((kt + 1) * 32, cb ^ 1);
        bf16x8 av[4], bv[4];
#pragma unroll
        for (int i = 0; i < 4; i++)
            av[i] = *(const bf16x8*)&As[cb][(wm + i * 16 + fr) * 32 + fq * 8];
#pragma unroll
        for (int j = 0; j < 4; j++)
            bv[j] = *(const bf16x8*)&Bs[cb][(wn + j * 16 + fr) * 32 + fq * 8];
#pragma unroll
        for (int i = 0; i < 4; i++)
#pragma unroll
            for (int j = 0; j < 4; j++)
                acc[i][j] = __builtin_amdgcn_mfma_f32_16x16x32_bf16(av[i], bv[j], acc[i][j], 0, 0, 0);
        __syncthreads();
    }

#pragma unroll
    for (int i = 0; i < 4; i++) {
#pragma unroll
        for (int j = 0; j < 4; j++) {
#pragma unroll
            for (int r2 = 0; r2 < 4; r2++) {
                int row = bm + wm + i * 16 + fq * 4 + r2;
                int col = bn + wn + j * 16 + fr;
                if (row < M) C[(size_t)row * N + col] = __float2bfloat16(acc[i][j][r2]);
            }
        }
    }

    // ---- fused layer-2 e partials ----
    float asv[4], adv[4];
#pragma unroll
    for (int j = 0; j < 4; j++) {
        asv[j] = a_src2[bn + wn + j * 16 + fr];
        adv[j] = a_dst2[bn + wn + j * 16 + fr];
    }
    __syncthreads();
    float* eb = (float*)&As[0][0];
#pragma unroll
    for (int i = 0; i < 4; i++) {
#pragma unroll
        for (int r2 = 0; r2 < 4; r2++) {
            float ps = 0.f, pd = 0.f;
#pragma unroll
            for (int j = 0; j < 4; j++) { ps += acc[i][j][r2] * asv[j]; pd += acc[i][j][r2] * adv[j]; }
#pragma unroll
            for (int o = 8; o >= 1; o >>= 1) { ps += __shfl_xor(ps, o, 64); pd += __shfl_xor(pd, o, 64); }
            if (fr == 0) {
                int rowl = wm + i * 16 + fq * 4 + r2;
                int wnIdx = wn >> 6;
                eb[(rowl * 2 + wnIdx) * 2 + 0] = ps;
                eb[(rowl * 2 + wnIdx) * 2 + 1] = pd;
            }
        }
    }
    __syncthreads();
    if (t < 128) {
        int row = bm + t;
        if (row < M) {
            atomicAdd(&esrc[row], eb[t * 4 + 0] + eb[t * 4 + 2]);
            atomicAdd(&edst[row], eb[t * 4 + 1] + eb[t * 4 + 3]);
        }
    }
}

// ---------------- CSR build ----------------
__global__ void hist_kernel(const int* __restrict__ ei, int* __restrict__ deg) {
    int e = blockIdx.x * 256 + threadIdx.x;
    if (e >= EL) return;
    int d = (e < E0) ? ei[E0 + e] : (e - E0);
    atomicAdd(&deg[d], 1);
}

__global__ __launch_bounds__(1024)
void scan_blk(const int* __restrict__ deg, int* __restrict__ off, int* __restrict__ bsum) {
    __shared__ int wsum[16];
    const int b = blockIdx.x, t = threadIdx.x, lane = t & 63, wv = t >> 6;
    const int i = b * 1024 + t;
    int v = (i < NN) ? deg[i] : 0;
    int x = v;
#pragma unroll
    for (int o = 1; o < 64; o <<= 1) {
        int y = __shfl_up(x, o, 64);
        if (lane >= o) x += y;
    }
    if (lane == 63) wsum[wv] = x;
    __syncthreads();
    if (wv == 0 && lane < 16) {
        int s = wsum[lane];
#pragma unroll
        for (int o = 1; o < 16; o <<= 1) {
            int y = __shfl_up(s, o, 64);
            if (lane >= o) s += y;
        }
        wsum[lane] = s;
    }
    __syncthreads();
    int woff = (wv == 0) ? 0 : wsum[wv - 1];
    if (i < NN) off[i + 1] = woff + x;
    if (t == 1023) bsum[b] = wsum[15];
}

__global__ __launch_bounds__(1024)
void scan_add(int* __restrict__ off, const int* __restrict__ bsum) {
    __shared__ int boffs[NSB];
    const int b = blockIdx.x, t = threadIdx.x;
    if (t < 64) {
        int lane = t;
        int v = (lane < NSB) ? bsum[lane] : 0;
        int x = v;
#pragma unroll
        for (int o = 1; o < 64; o <<= 1) {
            int y = __shfl_up(x, o, 64);
            if (lane >= o) x += y;
        }
        if (lane < NSB) boffs[lane] = x - v;   // exclusive
    }
    __syncthreads();
    const int i = b * 1024 + t;
    if (i < NN) off[i + 1] += boffs[b];
    if (b == 0 && t == 0) off[0] = 0;
}

// ---------------- GAT aggregation: one WAVE per (node, head) pair ----------------
template<int H, bool RELU, typename OutT>
__global__ __launch_bounds__(256)
void gat_aggregate(const __hip_bfloat16* __restrict__ hfeat,
                   const float* __restrict__ esrc,
                   const float* __restrict__ edst,
                   const int* __restrict__ off, const int* __restrict__ csr,
                   const float* __restrict__ bias,
                   OutT* __restrict__ out, int N) {
    const int wv = threadIdx.x >> 6, lane = threadIdx.x & 63;
    const int pair = blockIdx.x * 4 + wv;
    if (pair >= N * H) return;
    const int n = pair / H;
    const int h = pair - n * H;
    const int beg = off[n];
    const int deg = off[n + 1] - beg;

    const float ed = edst[n * H + h];
    float m = -INFINITY, den = 0.f;
    f32x4 acc = (f32x4){0.f, 0.f, 0.f, 0.f};

    for (int base = 0; base < deg; base += 64) {
        const int i = base + lane;
        int s = 0;
        float lg = -INFINITY;
        if (i < deg) {
            s = csr[beg + i];
            float v = esrc[s * H + h] + ed;
            lg = (v >= 0.f) ? v : NEG_SLOPE * v;
        }
        float cm = lg;
#pragma unroll
        for (int o = 1; o < 64; o <<= 1)
            cm = fmaxf(cm, __shfl_xor(cm, o, 64));
        float nm = fmaxf(m, cm);
        float sc = expf(m - nm);
        den *= sc;
#pragma unroll
        for (int e = 0; e < 4; e++) acc[e] *= sc;
        m = nm;
        float wgt = (i < deg) ? expf(lg - m) : 0.f;
        den += wgt;
        const int cnt = min(64, deg - base);
        for (int j = 0; j < cnt; j++) {
            int sj = __shfl(s, j, 64);
            float wj = __shfl(wgt, j, 64);
            bf16x4 hv = *(const bf16x4*)(hfeat + (size_t)sj * (H * 256) + h * 256 + 4 * lane);
#pragma unroll
            for (int e = 0; e < 4; e++) acc[e] += wj * (float)hv[e];
        }
    }
#pragma unroll
    for (int o = 1; o < 64; o <<= 1) den += __shfl_xor(den, o, 64);

    float inv = 1.f / (den + 1e-16f);
    if constexpr (sizeof(OutT) == 2) {
        bf16x4 r;
#pragma unroll
        for (int e = 0; e < 4; e++) {
            float f = acc[e] * inv + bias[h * 256 + 4 * lane + e];
            if (RELU) f = fmaxf(f, 0.f);
            r[e] = (__bf16)f;
        }
        *(bf16x4*)((__hip_bfloat16*)out + (size_t)n * (H * 256) + h * 256 + 4 * lane) = r;
    } else {
        float4 r;
        float* rp = &r.x;
#pragma unroll
        for (int e = 0; e < 4; e++) {
            float f = acc[e] * inv + bias[h * 256 + 4 * lane + e];
            if (RELU) f = fmaxf(f, 0.f);
            rp[e] = f;
        }
        *(float4*)((float*)out + (size_t)n * (H * 256) + h * 256 + 4 * lane) = r;
    }
}

// ---------------- pooling: high-parallelism partial sums (2048 blocks, 4-way ILP) ----------------
__device__ __forceinline__ int lower_bound_batch(const int* __restrict__ batch, int key) {
    int lo = 0, hi = NN;
    while (lo < hi) {
        int mid = (lo + hi) >> 1;
        if (batch[mid] < key) lo = mid + 1; else hi = mid;
    }
    return lo;
}

__global__ __launch_bounds__(256)
void pool_partial(const __hip_bfloat16* __restrict__ out2, const int* __restrict__ batch,
                  float* __restrict__ partial, float* __restrict__ cnts) {
    const int g = blockIdx.x, c = blockIdx.y, t = threadIdx.x;
    const int s = lower_bound_batch(batch, g);
    const int e = lower_bound_batch(batch, g + 1);
    float a0 = 0.f, a1 = 0.f, a2 = 0.f, a3 = 0.f;
    int n = s + c;
    for (; n + 3 * PCH < e; n += 4 * PCH) {
        float v0 = __bfloat162float(out2[(size_t)n * 256 + t]);
        float v1 = __bfloat162float(out2[(size_t)(n + PCH) * 256 + t]);
        float v2 = __bfloat162float(out2[(size_t)(n + 2 * PCH) * 256 + t]);
        float v3 = __bfloat162float(out2[(size_t)(n + 3 * PCH) * 256 + t]);
        a0 += v0; a1 += v1; a2 += v2; a3 += v3;
    }
    for (; n < e; n += PCH) a0 += __bfloat162float(out2[(size_t)n * 256 + t]);
    partial[((size_t)g * PCH + c) * 256 + t] = a0 + a1 + a2 + a3;
    if (t == 0 && c == 0) cnts[g] = (float)(e - s);
}

// ---------------- MLP head + softmax (folds PCH partials) ----------------
__global__ __launch_bounds__(256)
void head_kernel(const float* __restrict__ partial, const float* __restrict__ cnts,
                 const float* __restrict__ phy,
                 const float* __restrict__ w11, const float* __restrict__ b11,
                 const float* __restrict__ w12, const float* __restrict__ b12,
                 const float* __restrict__ w21, const float* __restrict__ b21,
                 const float* __restrict__ w22, const float* __restrict__ b22,
                 float* __restrict__ out) {
    int g = blockIdx.x, t = threadIdx.x;
    __shared__ float ph[188];
    __shared__ float z[384];
    __shared__ float mid[128];
    __shared__ float t1[192];
    __shared__ float lg[2];
    if (t < 188) ph[t] = phy[g * 188 + t];
    {
        float s = 0.f;
#pragma unroll
        for (int c = 0; c < PCH; c++) s += partial[((size_t)g * PCH + c) * 256 + t];
        z[t] = s / fmaxf(cnts[g], 1.0f);
    }
    __syncthreads();
    if (t < 128) {
        float sm = b11[t];
        for (int k = 0; k < 188; k++) sm += ph[k] * w11[k * 128 + t];
        mid[t] = fmaxf(sm, 0.f);
    }
    __syncthreads();
    if (t < 128) {
        float sm = b12[t];
        for (int k = 0; k < 128; k++) sm += mid[k] * w12[k * 128 + t];
        z[256 + t] = fmaxf(sm, 0.f);
    }
    __syncthreads();
    if (t < 192) {
        float sm = b21[t];
        for (int k = 0; k < 384; k++) sm += z[k] * w21[k * 192 + t];
        t1[t] = fmaxf(sm, 0.f);
    }
    __syncthreads();
    if (t < 2) {
        float sm = b22[t];
        for (int k = 0; k < 192; k++) sm += t1[k] * w22[k * 2 + t];
        lg[t] = sm;
    }
    __syncthreads();
    if (t == 0) {
        float mx = fmaxf(lg[0], lg[1]);
        float e0 = expf(lg[0] - mx), e1 = expf(lg[1] - mx);
        float d = e0 + e1;
        out[g * 2 + 0] = e0 / d;
        out[g * 2 + 1] = e1 / d;
    }
}

extern "C" void kernel_launch(void* const* d_in, const int* in_sizes, int n_in,
                              void* d_out, int out_size, void* d_ws, size_t ws_size,
                              hipStream_t stream) {
    const float* x       = (const float*)d_in[0];
    const int*   ei      = (const int*)  d_in[1];
    const float* phy     = (const float*)d_in[2];
    const int*   batch   = (const int*)  d_in[3];
    const float* W1      = (const float*)d_in[4];
    const float* a_src1  = (const float*)d_in[5];
    const float* a_dst1  = (const float*)d_in[6];
    const float* b1      = (const float*)d_in[7];
    const float* W2      = (const float*)d_in[8];
    const float* a_src2  = (const float*)d_in[9];
    const float* a_dst2  = (const float*)d_in[10];
    const float* b2      = (const float*)d_in[11];
    const float* fc1_w1  = (const float*)d_in[12];
    const float* fc1_b1  = (const float*)d_in[13];
    const float* fc1_w2  = (const float*)d_in[14];
    const float* fc1_b2  = (const float*)d_in[15];
    const float* fc2_w1  = (const float*)d_in[16];
    const float* fc2_b1  = (const float*)d_in[17];
    const float* fc2_w2  = (const float*)d_in[18];
    const float* fc2_b2  = (const float*)d_in[19];
    float* out = (float*)d_out;

    char* base = (char*)d_ws;
    size_t o = 0;
    auto alloc = [&](size_t bytes) { size_t r = o; o += (bytes + 255) & ~255ULL; return r; };

    size_t o_xb   = alloc((size_t)MP1 * K1P * 2);    // reused for h2b/out2 after GEMM1
    size_t o_w1t  = alloc((size_t)768 * K1P * 2);
    size_t o_w2t  = alloc((size_t)256 * 768 * 2);
    size_t o_h1b  = alloc((size_t)NP * 768 * 2);
    size_t o_hob  = alloc((size_t)NP * 768 * 2);
    size_t o_es1  = alloc((size_t)NN * 3 * 4);
    size_t o_ed1  = alloc((size_t)NN * 3 * 4);
    // zero region: es2, ed2, deg, cur contiguous
    size_t o_es2  = alloc((size_t)NN * 4);
    size_t o_ed2  = alloc((size_t)NN * 4);
    size_t o_deg  = alloc((size_t)(NN + 1) * 4);
    size_t o_cur  = alloc((size_t)NN * 4);
    size_t o_zend = o;
    size_t o_off  = alloc((size_t)(NN + 1) * 4);
    size_t o_csr  = alloc((size_t)EL * 4);
    size_t o_bsum = alloc((size_t)NSB * 4);
    size_t o_part = alloc((size_t)NG * PCH * 256 * 4);
    size_t o_cnts = alloc((size_t)NG * 4);

    __hip_bfloat16* xb   = (__hip_bfloat16*)(base + o_xb);
    __hip_bfloat16* w1t  = (__hip_bfloat16*)(base + o_w1t);
    __hip_bfloat16* w2t  = (__hip_bfloat16*)(base + o_w2t);
    __hip_bfloat16* h1b  = (__hip_bfloat16*)(base + o_h1b);
    __hip_bfloat16* hob  = (__hip_bfloat16*)(base + o_hob);
    __hip_bfloat16* h2b  = (__hip_bfloat16*)(base + o_xb);
    __hip_bfloat16* out2 = (__hip_bfloat16*)(base + o_xb + (size_t)24 * 1024 * 1024);
    float* es1   = (float*)(base + o_es1);
    float* ed1   = (float*)(base + o_ed1);
    float* es2   = (float*)(base + o_es2);
    float* ed2   = (float*)(base + o_ed2);
    int*   deg   = (int*)(base + o_deg);
    int*   cur   = (int*)(base + o_cur);
    int*   offs  = (int*)(base + o_off);
    int*   csr   = (int*)(base + o_csr);
    int*   bsum  = (int*)(base + o_bsum);
    float* part  = (float*)(base + o_part);
    float* cnts  = (float*)(base + o_cnts);

    // merged init: zero(es2,ed2,deg,cur) + convert_x + convert_w (one launch)
    {
        int n16 = (int)((o_zend - o_es2) / 16);
        init_kernel<<<ZB + XB + WB, 256, 0, stream>>>((uint4*)(base + o_es2), n16,
                                                      x, xb, W1, W2, w1t, w2t);
    }

    hist_kernel<<<(EL + 255) / 256, 256, 0, stream>>>(ei, deg);
    scan_blk<<<NSB, 1024, 0, stream>>>(deg, offs, bsum);
    scan_add<<<NSB, 1024, 0, stream>>>(offs, bsum);

    gemm256<<<NWG1 + FB, 512, 0, stream>>>(xb, w1t, h1b, a_src1, a_dst1, es1, ed1, NN,
                                           ei, offs, cur, csr);
    gat_aggregate<3, true, __hip_bfloat16><<<(NN * 3 + 3) / 4, 256, 0, stream>>>(h1b, es1, ed1, offs, csr, b1, hob, NN);

    gemm2_fused<<<2 * 157, 256, 0, stream>>>(hob, w2t, h2b, a_src2, a_dst2, es2, ed2, NN, 256, 768, 2);
    gat_aggregate<1, false, __hip_bfloat16><<<(NN + 3) / 4, 256, 0, stream>>>(h2b, es2, ed2, offs, csr, b2, out2, NN);

    pool_partial<<<dim3(NG, PCH), 256, 0, stream>>>(out2, batch, part, cnts);
    head_kernel<<<NG, 256, 0, stream>>>(part, cnts, phy,
                                        fc1_w1, fc1_b1, fc1_w2, fc1_b2,
                                        fc2_w1, fc2_b1, fc2_w2, fc2_b2, out);
}